// Round 11
// baseline (72.344 us; speedup 1.0000x reference)
//
#include <hip/hip_runtime.h>
#include <stdint.h>

typedef __bf16 bf16x8 __attribute__((ext_vector_type(8)));
typedef float  f32x4  __attribute__((ext_vector_type(4)));
typedef float  f32x16 __attribute__((ext_vector_type(16)));

#define NB 8
#define NT 2048
#define NC 1024
#define NH 64

#define WSWZ_BYTES (32 * 12 * 64 * 8 * 2)   // 384 KB swizzled W frags
#define QK_BYTES   (NB * NT * NH * 2)       // 2 MB each for Q, K, V^T (bf16)

// 32x32 attention: QBLK=32 (q-tiles 0..63/batch), KVBLK=64, segments of 2 steps.
#define SEG_PER_B 544
#define SLOTS     (NB * SEG_PER_B)          // 4352
#define PO_OFF    (WSWZ_BYTES + 3 * QK_BYTES)
#define PO_BYTES  (SLOTS * 32 * 64 * 2)     // bf16 partial O, [slot][q32][d64]
#define PM_OFF    (PO_OFF + PO_BYTES)
#define PM_BYTES  (SLOTS * 32 * 4)
#define PL_OFF    (PM_OFF + PM_BYTES)

#define SOFTMAX_SC 0.18033688011112042f     // 0.125 * log2(e)
#define MASK_VAL  (-30000.0f)               // safe-range sentinel
#define MINIT_VAL (-10000.0f)

// ---------------------------------------------------------------------------
__device__ __forceinline__ unsigned cvtpk(float lo, float hi) {
  unsigned r;
  asm("v_cvt_pk_bf16_f32 %0, %1, %2" : "=v"(r) : "v"(lo), "v"(hi));
  return r;
}
__device__ __forceinline__ bf16x8 cvt8(f32x4 f0, f32x4 f1) {
  bf16x8 h;
  h[0] = (__bf16)f0[0]; h[1] = (__bf16)f0[1]; h[2] = (__bf16)f0[2]; h[3] = (__bf16)f0[3];
  h[4] = (__bf16)f1[0]; h[5] = (__bf16)f1[1]; h[6] = (__bf16)f1[2]; h[7] = (__bf16)f1[3];
  return h;
}

// ---------------------------------------------------------------------------
// Kernel 0: swizzle concat(Wq,Wk,Wv) [1024][192] f32 -> bf16 MFMA B-fragments.
__global__ __launch_bounds__(64) void sdpa_prep_w(
    const float* __restrict__ Wq, const float* __restrict__ Wk,
    const float* __restrict__ Wv, __bf16* __restrict__ wswz) {
  const int blk = blockIdx.x;            // 384 = 32 kb * 12 nf
  const int kb = blk / 12, nf = blk % 12;
  const int l = threadIdx.x;
  const float* W = (nf < 4) ? Wq : ((nf < 8) ? Wk : Wv);
  const int col = ((nf & 3) << 4) + (l & 15);
  const int c0 = kb * 32 + ((l >> 4) << 3);
  union { __bf16 h[8]; uint4 u; } pk;
#pragma unroll
  for (int j = 0; j < 8; ++j) pk.h[j] = (__bf16)W[(size_t)(c0 + j) * NH + col];
  *reinterpret_cast<uint4*>(wswz + ((size_t)blk * 64 + l) * 8) = pk.u;
}

// ---------------------------------------------------------------------------
// Kernel 1: QKV projection. BM=64, grid 256 (1 block/CU), 256 thr (4 waves).
// Traffic: 256 x (256KB x + 384KB w) = 164 MB total (vs 265-460 MB before).
// x panel LDS-resident as bf16, 2 halves of 64KB, reg-staged with XOR swizzle.
// One barrier per half; half-1 loads issued before half-0's MFMA (T14).
__global__ __launch_bounds__(256) void sdpa_qkv(
    const float* __restrict__ x, const __bf16* __restrict__ wswz,
    __bf16* __restrict__ Qb, __bf16* __restrict__ Kb, __bf16* __restrict__ VTb) {
  __shared__ __attribute__((aligned(16))) __bf16 xpan[2 * 64 * 512];  // 128 KB
  __shared__ __attribute__((aligned(16))) __bf16 vt[64 * 72];         // 9 KB
  const int tid = threadIdx.x;
  const int w = tid >> 6, l = tid & 63;
  const int bid = blockIdx.x;
  const int lbid = ((bid & 7) << 5) | (bid >> 3);   // XCD-contiguous (256 = 8*32)
  const int r0 = lbid * 64;
  char* xpb = reinterpret_cast<char*>(xpan);
  const int arow = l & 15;

  // stage: thread covers float8 g8 = p*256 + tid (p 0..15) within a half.
  // row = g8>>6 (64 rows), cf = g8&63 (64 chunks of 16B after cvt).
  // Swizzled byte addr in half H:
  //   H*65536 + row*1024 + ((cf*16) ^ ((row&7)<<4) ^ (((cf>>4)&7)<<4))
#define SLD(S, P, H) do {                                                     \
    const int g8_ = (P) * 256 + tid;                                          \
    const float* sp_ = x + (size_t)(r0 + (g8_ >> 6)) * NC + (H) * 512         \
                         + (g8_ & 63) * 8;                                    \
    S##a = *reinterpret_cast<const f32x4*>(sp_);                              \
    S##b = *reinterpret_cast<const f32x4*>(sp_ + 4);                          \
  } while (0)
#define SWR(S, P, H) do {                                                     \
    const int g8_ = (P) * 256 + tid;                                          \
    const int row_ = g8_ >> 6, cf_ = g8_ & 63;                                \
    const int ad_ = (H) * 65536 + row_ * 1024 +                               \
        ((cf_ * 16) ^ ((row_ & 7) << 4) ^ (((cf_ >> 4) & 7) << 4));           \
    union { bf16x8 h; uint4 u; } pk_;                                         \
    pk_.h = cvt8(S##a, S##b);                                                 \
    *reinterpret_cast<uint4*>(xpb + ad_) = pk_.u;                             \
  } while (0)
#define STAGETAIL(H)                                                          \
    SWR(s0, 0, H);  SLD(s0, 4, H);                                            \
    SWR(s1, 1, H);  SLD(s1, 5, H);                                            \
    SWR(s2, 2, H);  SLD(s2, 6, H);                                            \
    SWR(s3, 3, H);  SLD(s3, 7, H);                                            \
    SWR(s0, 4, H);  SLD(s0, 8, H);                                            \
    SWR(s1, 5, H);  SLD(s1, 9, H);                                            \
    SWR(s2, 6, H);  SLD(s2, 10, H);                                           \
    SWR(s3, 7, H);  SLD(s3, 11, H);                                           \
    SWR(s0, 8, H);  SLD(s0, 12, H);                                           \
    SWR(s1, 9, H);  SLD(s1, 13, H);                                           \
    SWR(s2, 10, H); SLD(s2, 14, H);                                           \
    SWR(s3, 11, H); SLD(s3, 15, H);                                           \
    SWR(s0, 12, H); SWR(s1, 13, H); SWR(s2, 14, H); SWR(s3, 15, H)

#define LDB3(KS, DST) do {                                                    \
    _Pragma("unroll")                                                         \
    for (int nf_ = 0; nf_ < 3; ++nf_)                                         \
      DST[nf_] = *reinterpret_cast<const bf16x8*>(                            \
          wswz + (((size_t)(KS) * 12 + (w * 3 + nf_)) * 64 + l) * 8);         \
  } while (0)

#define CMP(H, KS, BF) do {                                                   \
    const int cf_ = (KS) * 4 + (l >> 4);                                      \
    bf16x8 afr_[4];                                                           \
    _Pragma("unroll")                                                         \
    for (int mf_ = 0; mf_ < 4; ++mf_) {                                       \
      const int row_ = mf_ * 16 + arow;                                       \
      const int ad_ = (H) * 65536 + row_ * 1024 +                             \
          ((cf_ * 16) ^ ((row_ & 7) << 4) ^ (((cf_ >> 4) & 7) << 4));         \
      afr_[mf_] = *reinterpret_cast<const bf16x8*>(xpb + ad_);                \
    }                                                                         \
    _Pragma("unroll")                                                         \
    for (int nf_ = 0; nf_ < 3; ++nf_)                                         \
      _Pragma("unroll")                                                       \
      for (int mf_ = 0; mf_ < 4; ++mf_)                                       \
        acc[mf_][nf_] = __builtin_amdgcn_mfma_f32_16x16x32_bf16(              \
            afr_[mf_], BF[nf_], acc[mf_][nf_], 0, 0, 0);                      \
  } while (0)

#define MFMAH(H) do {                                                         \
    bf16x8 B0[3], B1[3], B2[3], B3[3];                                        \
    LDB3((H) * 16 + 0, B0);  LDB3((H) * 16 + 1, B1);                          \
    LDB3((H) * 16 + 2, B2);  CMP(H, 0, B0);                                   \
    LDB3((H) * 16 + 3, B3);  CMP(H, 1, B1);                                   \
    LDB3((H) * 16 + 4, B0);  CMP(H, 2, B2);                                   \
    LDB3((H) * 16 + 5, B1);  CMP(H, 3, B3);                                   \
    LDB3((H) * 16 + 6, B2);  CMP(H, 4, B0);                                   \
    LDB3((H) * 16 + 7, B3);  CMP(H, 5, B1);                                   \
    LDB3((H) * 16 + 8, B0);  CMP(H, 6, B2);                                   \
    LDB3((H) * 16 + 9, B1);  CMP(H, 7, B3);                                   \
    LDB3((H) * 16 + 10, B2); CMP(H, 8, B0);                                   \
    LDB3((H) * 16 + 11, B3); CMP(H, 9, B1);                                   \
    LDB3((H) * 16 + 12, B0); CMP(H, 10, B2);                                  \
    LDB3((H) * 16 + 13, B1); CMP(H, 11, B3);                                  \
    LDB3((H) * 16 + 14, B2); CMP(H, 12, B0);                                  \
    LDB3((H) * 16 + 15, B3); CMP(H, 13, B1);                                  \
    CMP(H, 14, B2);                                                           \
    CMP(H, 15, B3);                                                           \
  } while (0)

  f32x4 acc[4][3];
#pragma unroll
  for (int mf = 0; mf < 4; ++mf)
#pragma unroll
    for (int nf = 0; nf < 3; ++nf) acc[mf][nf] = f32x4{0.f, 0.f, 0.f, 0.f};

  f32x4 s0a, s0b, s1a, s1b, s2a, s2b, s3a, s3b;
  // ---- stage half 0 ----
  SLD(s0, 0, 0); SLD(s1, 1, 0); SLD(s2, 2, 0); SLD(s3, 3, 0);
  STAGETAIL(0);
  __syncthreads();
  // ---- issue first half-1 loads early (arrive under MFMA half 0) ----
  SLD(s0, 0, 1); SLD(s1, 1, 1); SLD(s2, 2, 1); SLD(s3, 3, 1);
  __builtin_amdgcn_sched_barrier(0);
  // ---- MFMA half 0 (barrier-free; B lead-2) ----
  MFMAH(0);
  // ---- stage half 1 remainder ----
  STAGETAIL(1);
  __syncthreads();
  // ---- MFMA half 1 ----
  MFMAH(1);

  // Epilogue (R8-verified, BM=64). C-layout: col = l&15, row = (l>>4)*4 + r.
  const int batch = r0 >> 11;
  const int t0 = r0 & (NT - 1);
  const int ccol = l & 15, crow4 = (l >> 4) << 2;
#pragma unroll
  for (int mf = 0; mf < 4; ++mf)
#pragma unroll
    for (int nfl = 0; nfl < 3; ++nfl) {
      const int n16 = w * 3 + nfl;
      const int tensor = n16 >> 2;          // 0=Q 1=K 2=V
      const int grow = r0 + mf * 16 + crow4;
      if (tensor == 0) {
#pragma unroll
        for (int r = 0; r < 4; ++r)
          Qb[(size_t)(grow + r) * NH + ((n16 & 3) << 4) + ccol] = (__bf16)acc[mf][nfl][r];
      } else if (tensor == 1) {
#pragma unroll
        for (int r = 0; r < 4; ++r)
          Kb[(size_t)(grow + r) * NH + ((n16 & 3) << 4) + ccol] = (__bf16)acc[mf][nfl][r];
      } else {
        const int d = ((n16 & 3) << 4) + ccol;
        const int qloc = mf * 16 + crow4;
        uint2 pv;
        pv.x = cvtpk(acc[mf][nfl][0], acc[mf][nfl][1]);
        pv.y = cvtpk(acc[mf][nfl][2], acc[mf][nfl][3]);
        *reinterpret_cast<uint2*>(reinterpret_cast<char*>(vt) + (d * 72 + qloc) * 2) = pv;
      }
    }
  __syncthreads();
  {
    const int d = tid >> 2, part = tid & 3;
    const char* src = reinterpret_cast<const char*>(vt) + (d * 72 + part * 16) * 2;
    const uint4 v0 = *reinterpret_cast<const uint4*>(src);
    const uint4 v1 = *reinterpret_cast<const uint4*>(src + 16);
    __bf16* dst = VTb + (size_t)(batch * 64 + d) * NT + t0 + part * 16;
    *reinterpret_cast<uint4*>(dst) = v0;
    *reinterpret_cast<uint4*>(dst + 8) = v1;
  }
#undef SLD
#undef SWR
#undef STAGETAIL
#undef LDB3
#undef CMP
#undef MFMAH
}

// ---------------------------------------------------------------------------
// Kernel 2: attention segment, 32x32 MFMA, swapped QK^T (S^T = K Q^T), all
// softmax + P-layout conversion in registers (no LDS, no barriers).
// D-layout (32x32): col=l&31, row=(r&3)+8*(r>>2)+4*(l>>5). Segment = 2 tiles.
__global__ __launch_bounds__(64) void sdpa_attn_seg(
    const __bf16* __restrict__ Qb, const __bf16* __restrict__ Kb,
    const __bf16* __restrict__ VTb, __bf16* __restrict__ po,
    float* __restrict__ pm, float* __restrict__ pl) {
  const int l = threadIdx.x;
  const int bid = blockIdx.x;
  const int b = bid & 7;                  // XCD-pinned batch
  const int s = bid >> 3;
  // slot -> (qt, seg): qts grouped by m = qt>>1 (nkt = m+1, cnt = ceil((m+1)/2))
  int m = 0, base = 0;
  while (true) {
    const int c = (m + 2) & ~1;           // 2 * ceil((m+1)/2)
    if (s < base + c) break;
    base += c; ++m;
  }
  const int rem = s - base;
  const int cnt = (m + 2) >> 1;
  const int qt = 2 * m + (rem >= cnt ? 1 : 0);
  const int seg = rem - (rem >= cnt ? cnt : 0);
  const int nkt = m + 1;
  const int ndiag = nkt - 1;
  const int kt0 = seg * 2;
  const int kt1 = (kt0 + 2 < nkt) ? (kt0 + 2) : nkt;

  const __bf16* Qp = Qb + (size_t)b * NT * NH;
  const __bf16* Kp = Kb + (size_t)b * NT * NH;
  const __bf16* Vp = VTb + (size_t)b * NH * NT;
  const int lq = l & 31, hi = l >> 5;
  const int q0 = qt * 32;
  const int qa = q0 + lq;

  bf16x8 qf[4];
#pragma unroll
  for (int ks = 0; ks < 4; ++ks)
    qf[ks] = *reinterpret_cast<const bf16x8*>(Qp + (size_t)(q0 + lq) * NH + ks * 16 + hi * 8);

  f32x16 o0 = {}, o1 = {};
  float mreg = MINIT_VAL, lsum = 0.f;

  bf16x8 kc[8], kn[8], vv[8];
#pragma unroll
  for (int t = 0; t < 2; ++t)
#pragma unroll
    for (int ks = 0; ks < 4; ++ks)
      kc[t * 4 + ks] = *reinterpret_cast<const bf16x8*>(
          Kp + (size_t)(kt0 * 64 + 32 * t + lq) * NH + ks * 16 + hi * 8);

  for (int kt = kt0; kt < kt1; ++kt) {
    // V loads issued first; consumed after softmax (latency hidden)
#pragma unroll
    for (int dt = 0; dt < 2; ++dt)
#pragma unroll
      for (int ks = 0; ks < 4; ++ks)
        vv[dt * 4 + ks] = *reinterpret_cast<const bf16x8*>(
            Vp + (size_t)(32 * dt + lq) * NT + kt * 64 + ks * 16 + hi * 8);

    f32x16 s0 = {}, s1 = {};
    __builtin_amdgcn_s_setprio(1);
#pragma unroll
    for (int ks = 0; ks < 4; ++ks)
      s0 = __builtin_amdgcn_mfma_f32_32x32x16_bf16(kc[ks], qf[ks], s0, 0, 0, 0);
#pragma unroll
    for (int ks = 0; ks < 4; ++ks)
      s1 = __builtin_amdgcn_mfma_f32_32x32x16_bf16(kc[4 + ks], qf[ks], s1, 0, 0, 0);
    __builtin_amdgcn_s_setprio(0);

    const bool more = (kt + 1 < kt1);
    if (more) {                            // prefetch next K tile
#pragma unroll
      for (int t = 0; t < 2; ++t)
#pragma unroll
        for (int ks = 0; ks < 4; ++ks)
          kn[t * 4 + ks] = *reinterpret_cast<const bf16x8*>(
              Kp + (size_t)((kt + 1) * 64 + 32 * t + lq) * NH + ks * 16 + hi * 8);
    }

    if (kt == ndiag) {                     // causal mask (safe sentinel)
#pragma unroll
      for (int r = 0; r < 16; ++r) {
        const int kvr = kt * 64 + (r & 3) + 8 * (r >> 2) + 4 * hi;
        if (kvr > qa) s0[r] = MASK_VAL;
        if (kvr + 32 > qa) s1[r] = MASK_VAL;
      }
    }

    // row max: in-register tree over own 16, then cross-half shfl
    float t16[16];
#pragma unroll
    for (int r = 0; r < 16; ++r) t16[r] = fmaxf(s0[r], s1[r]);
#pragma unroll
    for (int wdt = 8; wdt > 0; wdt >>= 1)
#pragma unroll
      for (int r = 0; r < 16; ++r) if (r < wdt) t16[r] = fmaxf(t16[r], t16[r + wdt]);
    const float pmax = fmaxf(t16[0], __shfl_xor(t16[0], 32));
    const float mn = fmaxf(mreg, pmax);
    const float esc = exp2f(fminf((mreg - mn) * SOFTMAX_SC, 0.f));
    const float msc = mn * SOFTMAX_SC;
    mreg = mn;
#pragma unroll
    for (int r = 0; r < 16; ++r)
      s0[r] = exp2f(fminf(fmaf(s0[r], SOFTMAX_SC, -msc), 0.f));
#pragma unroll
    for (int r = 0; r < 16; ++r)
      s1[r] = exp2f(fminf(fmaf(s1[r], SOFTMAX_SC, -msc), 0.f));
#pragma unroll
    for (int r = 0; r < 16; ++r) t16[r] = s0[r] + s1[r];
#pragma unroll
    for (int wdt = 8; wdt > 0; wdt >>= 1)
#pragma unroll
      for (int r = 0; r < 16; ++r) if (r < wdt) t16[r] += t16[r + wdt];
    const float rs = t16[0] + __shfl_xor(t16[0], 32);
    lsum = lsum * esc + rs;
    o0 *= esc; o1 *= esc;

    // P^T (D-layout f32) -> B-fragments, direction-proof cross-half routing.
    __builtin_amdgcn_s_setprio(1);
#pragma unroll
    for (int ks16 = 0; ks16 < 4; ++ks16) {
      const f32x16& pt = (ks16 < 2) ? s0 : s1;
      const int base8 = 8 * (ks16 & 1);
      const unsigned w0 = cvtpk(pt[base8 + 0], pt[base8 + 1]);
      const unsigned w1 = cvtpk(pt[base8 + 2], pt[base8 + 3]);
      const unsigned w2 = cvtpk(pt[base8 + 4], pt[base8 + 5]);
      const unsigned w3 = cvtpk(pt[base8 + 6], pt[base8 + 7]);
      const unsigned m_a = hi ? w0 : w2;
      const unsigned m_b = hi ? w1 : w3;
      const unsigned e_a = __shfl_xor(m_a, 32);
      const unsigned e_b = __shfl_xor(m_b, 32);
      union { unsigned u[4]; bf16x8 v; } pb;
      pb.u[0] = hi ? e_a : w0;
      pb.u[1] = hi ? e_b : w1;
      pb.u[2] = hi ? w2 : e_a;
      pb.u[3] = hi ? w3 : e_b;
      o0 = __builtin_amdgcn_mfma_f32_32x32x16_bf16(vv[ks16], pb.v, o0, 0, 0, 0);
      o1 = __builtin_amdgcn_mfma_f32_32x32x16_bf16(vv[4 + ks16], pb.v, o1, 0, 0, 0);
    }
    __builtin_amdgcn_s_setprio(0);

    if (more) {
#pragma unroll
      for (int i = 0; i < 8; ++i) kc[i] = kn[i];
    }
  }

  // write partials: po[slot][q 32][d 64] bf16 (unnormalized), pm/pl per row
  const int slot = b * SEG_PER_B + s;
  __bf16* pop = po + (size_t)slot * 2048;
#pragma unroll
  for (int dt = 0; dt < 2; ++dt) {
    const f32x16& ov = dt ? o1 : o0;
#pragma unroll
    for (int u = 0; u < 4; ++u) {
      uint2 val;
      val.x = cvtpk(ov[4 * u + 0], ov[4 * u + 1]);
      val.y = cvtpk(ov[4 * u + 2], ov[4 * u + 3]);
      *reinterpret_cast<uint2*>(pop + lq * 64 + 8 * u + 4 * hi + 32 * dt) = val;
    }
  }
  if (hi == 0) {
    pm[slot * 32 + lq] = mreg;
    pl[slot * 32 + lq] = lsum;
  }
}

// ---------------------------------------------------------------------------
// Kernel 3: combine <=16 segments per q-tile (32 rows), normalize, f32 out.
__global__ __launch_bounds__(256) void sdpa_combine(
    const __bf16* __restrict__ po, const float* __restrict__ pm,
    const float* __restrict__ pl, float* __restrict__ out) {
  const int bid = blockIdx.x;              // 512: (qt<<3) | b
  const int b = bid & 7, qt = bid >> 3;
  const int mg = qt >> 1;
  int base = 0;
  for (int mm = 0; mm < mg; ++mm) base += (mm + 2) & ~1;
  const int cnt = (mg + 2) >> 1;
  base += (qt & 1) ? cnt : 0;
  const int nseg = cnt;                    // ceil(nkt/2), nkt = mg+1
  const int sbase = b * SEG_PER_B + base;
  const int t = threadIdx.x;
  const int r = t >> 3, dc = (t & 7) << 3;

  float M = MASK_VAL;
  for (int s = 0; s < nseg; ++s) M = fmaxf(M, pm[(sbase + s) * 32 + r]);
  float L = 0.f;
  float acc[8] = {0.f, 0.f, 0.f, 0.f, 0.f, 0.f, 0.f, 0.f};
  for (int s = 0; s < nseg; ++s) {
    const int slot = sbase + s;
    const float w = exp2f(fminf((pm[slot * 32 + r] - M) * SOFTMAX_SC, 0.f));
    L += pl[slot * 32 + r] * w;
    const bf16x8 v = *reinterpret_cast<const bf16x8*>(po + (size_t)slot * 2048 + r * 64 + dc);
#pragma unroll
    for (int j = 0; j < 8; ++j) acc[j] += w * (float)v[j];
  }
  const float inv = 1.f / L;
  float4 v0 = {acc[0] * inv, acc[1] * inv, acc[2] * inv, acc[3] * inv};
  float4 v1 = {acc[4] * inv, acc[5] * inv, acc[6] * inv, acc[7] * inv};
  float* dst = out + ((size_t)b * NT + qt * 32 + r) * NH + dc;
  *reinterpret_cast<float4*>(dst) = v0;
  *reinterpret_cast<float4*>(dst + 4) = v1;
}

// ---------------------------------------------------------------------------
extern "C" void kernel_launch(void* const* d_in, const int* in_sizes, int n_in,
                              void* d_out, int out_size, void* d_ws, size_t ws_size,
                              hipStream_t stream) {
  const float* x  = (const float*)d_in[0];
  const float* Wq = (const float*)d_in[1];
  const float* Wk = (const float*)d_in[2];
  const float* Wv = (const float*)d_in[3];
  char* ws = (char*)d_ws;
  __bf16* wswz = (__bf16*)(ws);
  __bf16* Qb   = (__bf16*)(ws + WSWZ_BYTES);
  __bf16* Kb   = (__bf16*)(ws + WSWZ_BYTES + QK_BYTES);
  __bf16* VTb  = (__bf16*)(ws + WSWZ_BYTES + 2 * (size_t)QK_BYTES);
  __bf16* po   = (__bf16*)(ws + PO_OFF);
  float*  pm   = (float*)(ws + PM_OFF);
  float*  pl   = (float*)(ws + PL_OFF);
  float* out = (float*)d_out;

  sdpa_prep_w<<<dim3(384), dim3(64), 0, stream>>>(Wq, Wk, Wv, wswz);
  sdpa_qkv<<<dim3(256), dim3(256), 0, stream>>>(x, wswz, Qb, Kb, VTb);
  sdpa_attn_seg<<<dim3(SLOTS), dim3(64), 0, stream>>>(Qb, Kb, VTb, po, pm, pl);
  sdpa_combine<<<dim3(NB * 64), dim3(256), 0, stream>>>(po, pm, pl, out);
}

// Round 12
// 62.619 us; speedup vs baseline: 1.1553x; 1.1553x over previous
//
#include <hip/hip_runtime.h>
#include <stdint.h>

typedef __bf16 bf16x8 __attribute__((ext_vector_type(8)));
typedef float  f32x4  __attribute__((ext_vector_type(4)));
typedef float  f32x16 __attribute__((ext_vector_type(16)));

#define NB 8
#define NT 2048
#define NC 1024
#define NH 64

#define WSWZ_BYTES (32 * 12 * 64 * 8 * 2)   // 384 KB swizzled W frags
#define QK_BYTES   (NB * NT * NH * 2)       // 2 MB each for Q, K, V^T (bf16)

// 32x32 attention: QBLK=32 (q-tiles 0..63/batch), KVBLK=64, segments of 4 steps.
// Per batch: sum over qt of ceil(nkt/4) = 288.
#define SEG_PER_B 288
#define SLOTS     (NB * SEG_PER_B)          // 2304
#define PO_OFF    (WSWZ_BYTES + 3 * QK_BYTES)
#define PO_BYTES  (SLOTS * 32 * 64 * 2)     // bf16 partial O, [slot][q32][d64]
#define PM_OFF    (PO_OFF + PO_BYTES)
#define PM_BYTES  (SLOTS * 32 * 4)
#define PL_OFF    (PM_OFF + PM_BYTES)

#define SOFTMAX_SC 0.18033688011112042f     // 0.125 * log2(e)
#define MASK_VAL  (-30000.0f)               // safe-range sentinel
#define MINIT_VAL (-10000.0f)
#define DEFER_THR 16.635f                   // 3.0 / SOFTMAX_SC (P <= 2^3)

// ---------------------------------------------------------------------------
__device__ __forceinline__ unsigned cvtpk(float lo, float hi) {
  unsigned r;
  asm("v_cvt_pk_bf16_f32 %0, %1, %2" : "=v"(r) : "v"(lo), "v"(hi));
  return r;
}
__device__ __forceinline__ bf16x8 cvt8(f32x4 f0, f32x4 f1) {
  bf16x8 h;
  h[0] = (__bf16)f0[0]; h[1] = (__bf16)f0[1]; h[2] = (__bf16)f0[2]; h[3] = (__bf16)f0[3];
  h[4] = (__bf16)f1[0]; h[5] = (__bf16)f1[1]; h[6] = (__bf16)f1[2]; h[7] = (__bf16)f1[3];
  return h;
}

// ---------------------------------------------------------------------------
// Kernel 0: swizzle concat(Wq,Wk,Wv) [1024][192] f32 -> bf16 MFMA B-fragments.
__global__ __launch_bounds__(64) void sdpa_prep_w(
    const float* __restrict__ Wq, const float* __restrict__ Wk,
    const float* __restrict__ Wv, __bf16* __restrict__ wswz) {
  const int blk = blockIdx.x;            // 384 = 32 kb * 12 nf
  const int kb = blk / 12, nf = blk % 12;
  const int l = threadIdx.x;
  const float* W = (nf < 4) ? Wq : ((nf < 8) ? Wk : Wv);
  const int col = ((nf & 3) << 4) + (l & 15);
  const int c0 = kb * 32 + ((l >> 4) << 3);
  union { __bf16 h[8]; uint4 u; } pk;
#pragma unroll
  for (int j = 0; j < 8; ++j) pk.h[j] = (__bf16)W[(size_t)(c0 + j) * NH + col];
  *reinterpret_cast<uint4*>(wswz + ((size_t)blk * 64 + l) * 8) = pk.u;
}

// ---------------------------------------------------------------------------
// Kernel 1: QKV projection (R10 version, best measured). BM=32, grid 512
// (2 blocks/CU), 256 thr. Whole 32x1024 x-panel staged ONCE to LDS as bf16;
// one barrier; barrier-free 32-step MFMA loop; B-frags lead-2, 4 buffers.
__global__ __launch_bounds__(256) void sdpa_qkv(
    const float* __restrict__ x, const __bf16* __restrict__ wswz,
    __bf16* __restrict__ Qb, __bf16* __restrict__ Kb, __bf16* __restrict__ VTb) {
  __shared__ __attribute__((aligned(16))) __bf16 xpan[32 * 1024];  // 64 KB
  __shared__ __attribute__((aligned(16))) __bf16 vt[64 * 40];      // 5 KB
  const int tid = threadIdx.x;
  const int w = tid >> 6, l = tid & 63;
  const int bid = blockIdx.x;
  const int lbid = ((bid & 7) << 6) | (bid >> 3);   // XCD-contiguous (512 = 8*64)
  const int r0 = lbid * 32;
  char* xpb = reinterpret_cast<char*>(xpan);

#define SLD(S, P) do {                                                        \
    const float* sp_ = x + (size_t)r0 * NC + (size_t)((P) * 256 + tid) * 8;   \
    S##a = *reinterpret_cast<const f32x4*>(sp_);                              \
    S##b = *reinterpret_cast<const f32x4*>(sp_ + 4);                          \
  } while (0)
#define SWR(S, P) do {                                                        \
    const int g8_ = (P) * 256 + tid;                                          \
    const int row_ = g8_ >> 7, cf_ = g8_ & 127;                               \
    const int ad_ = row_ * 2048 +                                             \
        ((cf_ * 16) ^ ((row_ & 7) << 4) ^ (((cf_ >> 4) & 7) << 4));           \
    union { bf16x8 h; uint4 u; } pk_;                                         \
    pk_.h = cvt8(S##a, S##b);                                                 \
    *reinterpret_cast<uint4*>(xpb + ad_) = pk_.u;                             \
  } while (0)

  {
    f32x4 s0a, s0b, s1a, s1b, s2a, s2b, s3a, s3b;
    SLD(s0, 0); SLD(s1, 1); SLD(s2, 2); SLD(s3, 3);
    SWR(s0, 0);  SLD(s0, 4);
    SWR(s1, 1);  SLD(s1, 5);
    SWR(s2, 2);  SLD(s2, 6);
    SWR(s3, 3);  SLD(s3, 7);
    SWR(s0, 4);  SLD(s0, 8);
    SWR(s1, 5);  SLD(s1, 9);
    SWR(s2, 6);  SLD(s2, 10);
    SWR(s3, 7);  SLD(s3, 11);
    SWR(s0, 8);  SLD(s0, 12);
    SWR(s1, 9);  SLD(s1, 13);
    SWR(s2, 10); SLD(s2, 14);
    SWR(s3, 11); SLD(s3, 15);
    SWR(s0, 12); SWR(s1, 13); SWR(s2, 14); SWR(s3, 15);
  }
  __syncthreads();                       // the ONLY pre-epilogue barrier

  const int arow = l & 15;
  const int albyte = (l >> 4) << 4;
  const int axorl = (arow & 7) << 4;
  const char* xr0 = xpb + arow * 2048;
  const char* xr1 = xpb + (16 + arow) * 2048;

#define LDB3(KS, DST) do {                                                    \
    _Pragma("unroll")                                                         \
    for (int nf_ = 0; nf_ < 3; ++nf_)                                         \
      DST[nf_] = *reinterpret_cast<const bf16x8*>(                            \
          wswz + (((size_t)(KS) * 12 + (w * 3 + nf_)) * 64 + l) * 8);         \
  } while (0)

#define CMP(KS, BF) do {                                                      \
    const int C_ = (((KS) * 64 + albyte) ^ axorl ^ ((((KS) >> 2) & 7) << 4)); \
    const bf16x8 a0_ = *reinterpret_cast<const bf16x8*>(xr0 + C_);            \
    const bf16x8 a1_ = *reinterpret_cast<const bf16x8*>(xr1 + C_);            \
    _Pragma("unroll")                                                         \
    for (int nf_ = 0; nf_ < 3; ++nf_) {                                       \
      acc[0][nf_] = __builtin_amdgcn_mfma_f32_16x16x32_bf16(                  \
          a0_, BF[nf_], acc[0][nf_], 0, 0, 0);                                \
      acc[1][nf_] = __builtin_amdgcn_mfma_f32_16x16x32_bf16(                  \
          a1_, BF[nf_], acc[1][nf_], 0, 0, 0);                                \
    }                                                                         \
  } while (0)

  f32x4 acc[2][3];
#pragma unroll
  for (int mf = 0; mf < 2; ++mf)
#pragma unroll
    for (int nf = 0; nf < 3; ++nf) acc[mf][nf] = f32x4{0.f, 0.f, 0.f, 0.f};

  bf16x8 B0[3], B1[3], B2[3], B3[3];
  LDB3(0, B0); LDB3(1, B1);
  for (int kq = 0; kq < 32; kq += 4) {
    LDB3(kq + 2, B2);
    CMP(kq + 0, B0);
    LDB3(kq + 3, B3);
    CMP(kq + 1, B1);
    if (kq + 4 < 32) LDB3(kq + 4, B0);
    CMP(kq + 2, B2);
    if (kq + 5 < 32) LDB3(kq + 5, B1);
    CMP(kq + 3, B3);
  }

  // Epilogue. C-layout per 16x16 frag: col = l&15, row = (l>>4)*4 + r.
  const int batch = r0 >> 11;
  const int t0 = r0 & (NT - 1);
  const int ccol = l & 15, crow4 = (l >> 4) << 2;
#pragma unroll
  for (int mf = 0; mf < 2; ++mf)
#pragma unroll
    for (int nfl = 0; nfl < 3; ++nfl) {
      const int n16 = w * 3 + nfl;
      const int tensor = n16 >> 2;          // 0=Q 1=K 2=V
      if (tensor == 0) {
#pragma unroll
        for (int r = 0; r < 4; ++r)
          Qb[(size_t)(r0 + mf * 16 + crow4 + r) * NH + ((n16 & 3) << 4) + ccol] =
              (__bf16)acc[mf][nfl][r];
      } else if (tensor == 1) {
#pragma unroll
        for (int r = 0; r < 4; ++r)
          Kb[(size_t)(r0 + mf * 16 + crow4 + r) * NH + ((n16 & 3) << 4) + ccol] =
              (__bf16)acc[mf][nfl][r];
      } else {
        const int d = ((n16 & 3) << 4) + ccol;
        const int qloc = mf * 16 + crow4;
        uint2 pv;
        pv.x = cvtpk(acc[mf][nfl][0], acc[mf][nfl][1]);
        pv.y = cvtpk(acc[mf][nfl][2], acc[mf][nfl][3]);
        *reinterpret_cast<uint2*>(reinterpret_cast<char*>(vt) + (d * 40 + qloc) * 2) = pv;
      }
    }
  __syncthreads();
  {
    const int d = tid >> 2, part = tid & 3;
    const uint4 v = *reinterpret_cast<const uint4*>(
        reinterpret_cast<const char*>(vt) + (d * 40 + part * 8) * 2);
    *reinterpret_cast<uint4*>(VTb + (size_t)(batch * 64 + d) * NT + t0 + part * 8) = v;
  }
#undef SLD
#undef SWR
#undef LDB3
#undef CMP
}

// ---------------------------------------------------------------------------
// Kernel 2: attention segment, 32x32 MFMA, swapped QK^T, in-register softmax.
// Segment = 4 KV tiles. Defer-max (T13): skip o-rescale when max growth <= THR.
// D-layout (32x32): col=l&31, row=(r&3)+8*(r>>2)+4*(l>>5).
__global__ __launch_bounds__(64) void sdpa_attn_seg(
    const __bf16* __restrict__ Qb, const __bf16* __restrict__ Kb,
    const __bf16* __restrict__ VTb, __bf16* __restrict__ po,
    float* __restrict__ pm, float* __restrict__ pl) {
  const int l = threadIdx.x;
  const int bid = blockIdx.x;
  const int b = bid & 7;                  // XCD-pinned batch
  const int s = bid >> 3;
  // slot -> (qt, seg): group by m = qt>>1; nkt = m+1; cnt = ceil(nkt/4) = (m+4)>>2
  int m = 0, base = 0;
  while (true) {
    const int c = 2 * ((m + 4) >> 2);
    if (s < base + c) break;
    base += c; ++m;
  }
  const int rem = s - base;
  const int cnt = (m + 4) >> 2;
  const int qt = 2 * m + (rem >= cnt ? 1 : 0);
  const int seg = rem - (rem >= cnt ? cnt : 0);
  const int nkt = m + 1;
  const int ndiag = nkt - 1;
  const int kt0 = seg * 4;
  const int kt1 = (kt0 + 4 < nkt) ? (kt0 + 4) : nkt;

  const __bf16* Qp = Qb + (size_t)b * NT * NH;
  const __bf16* Kp = Kb + (size_t)b * NT * NH;
  const __bf16* Vp = VTb + (size_t)b * NH * NT;
  const int lq = l & 31, hi = l >> 5;
  const int q0 = qt * 32;
  const int qa = q0 + lq;

  bf16x8 qf[4];
#pragma unroll
  for (int ks = 0; ks < 4; ++ks)
    qf[ks] = *reinterpret_cast<const bf16x8*>(Qp + (size_t)(q0 + lq) * NH + ks * 16 + hi * 8);

  f32x16 o0 = {}, o1 = {};
  float mreg = MINIT_VAL, lsum = 0.f;

  bf16x8 kc[8], kn[8], vv[8];
#pragma unroll
  for (int t = 0; t < 2; ++t)
#pragma unroll
    for (int ks = 0; ks < 4; ++ks)
      kc[t * 4 + ks] = *reinterpret_cast<const bf16x8*>(
          Kp + (size_t)(kt0 * 64 + 32 * t + lq) * NH + ks * 16 + hi * 8);

  for (int kt = kt0; kt < kt1; ++kt) {
    // V loads issued first; consumed after softmax (latency hidden)
#pragma unroll
    for (int dt = 0; dt < 2; ++dt)
#pragma unroll
      for (int ks = 0; ks < 4; ++ks)
        vv[dt * 4 + ks] = *reinterpret_cast<const bf16x8*>(
            Vp + (size_t)(32 * dt + lq) * NT + kt * 64 + ks * 16 + hi * 8);

    f32x16 s0 = {}, s1 = {};
    __builtin_amdgcn_s_setprio(1);
#pragma unroll
    for (int ks = 0; ks < 4; ++ks)
      s0 = __builtin_amdgcn_mfma_f32_32x32x16_bf16(kc[ks], qf[ks], s0, 0, 0, 0);
#pragma unroll
    for (int ks = 0; ks < 4; ++ks)
      s1 = __builtin_amdgcn_mfma_f32_32x32x16_bf16(kc[4 + ks], qf[ks], s1, 0, 0, 0);
    __builtin_amdgcn_s_setprio(0);

    const bool more = (kt + 1 < kt1);
    if (more) {                            // prefetch next K tile
#pragma unroll
      for (int t = 0; t < 2; ++t)
#pragma unroll
        for (int ks = 0; ks < 4; ++ks)
          kn[t * 4 + ks] = *reinterpret_cast<const bf16x8*>(
              Kp + (size_t)((kt + 1) * 64 + 32 * t + lq) * NH + ks * 16 + hi * 8);
    }

    if (kt == ndiag) {                     // causal mask (safe sentinel)
#pragma unroll
      for (int r = 0; r < 16; ++r) {
        const int kvr = kt * 64 + (r & 3) + 8 * (r >> 2) + 4 * hi;
        if (kvr > qa) s0[r] = MASK_VAL;
        if (kvr + 32 > qa) s1[r] = MASK_VAL;
      }
    }

    // row max: in-register tree over own 16, then cross-half shfl
    float t16[16];
#pragma unroll
    for (int r = 0; r < 16; ++r) t16[r] = fmaxf(s0[r], s1[r]);
#pragma unroll
    for (int wdt = 8; wdt > 0; wdt >>= 1)
#pragma unroll
      for (int r = 0; r < 16; ++r) if (r < wdt) t16[r] = fmaxf(t16[r], t16[r + wdt]);
    const float pmax = fmaxf(t16[0], __shfl_xor(t16[0], 32));
    // T13 defer-max: only rescale when some row grew past THR (wave-uniform)
    if (!__all(pmax - mreg <= DEFER_THR)) {
      const float mn = fmaxf(mreg, pmax);
      const float esc = exp2f(fminf((mreg - mn) * SOFTMAX_SC, 0.f));
      lsum *= esc;
      o0 *= esc; o1 *= esc;
      mreg = mn;
    }
    const float msc = mreg * SOFTMAX_SC;
    // exp args bounded by DEFER_THR*SC = 3 -> clamp at 3 (P <= 8, bf16-safe)
#pragma unroll
    for (int r = 0; r < 16; ++r)
      s0[r] = exp2f(fminf(fmaf(s0[r], SOFTMAX_SC, -msc), 3.0f));
#pragma unroll
    for (int r = 0; r < 16; ++r)
      s1[r] = exp2f(fminf(fmaf(s1[r], SOFTMAX_SC, -msc), 3.0f));
#pragma unroll
    for (int r = 0; r < 16; ++r) t16[r] = s0[r] + s1[r];
#pragma unroll
    for (int wdt = 8; wdt > 0; wdt >>= 1)
#pragma unroll
      for (int r = 0; r < 16; ++r) if (r < wdt) t16[r] += t16[r + wdt];
    lsum += t16[0] + __shfl_xor(t16[0], 32);

    // P^T (D-layout f32) -> B-fragments, direction-proof cross-half routing.
    __builtin_amdgcn_s_setprio(1);
#pragma unroll
    for (int ks16 = 0; ks16 < 4; ++ks16) {
      const f32x16& pt = (ks16 < 2) ? s0 : s1;
      const int base8 = 8 * (ks16 & 1);
      const unsigned w0 = cvtpk(pt[base8 + 0], pt[base8 + 1]);
      const unsigned w1 = cvtpk(pt[base8 + 2], pt[base8 + 3]);
      const unsigned w2 = cvtpk(pt[base8 + 4], pt[base8 + 5]);
      const unsigned w3 = cvtpk(pt[base8 + 6], pt[base8 + 7]);
      const unsigned m_a = hi ? w0 : w2;
      const unsigned m_b = hi ? w1 : w3;
      const unsigned e_a = __shfl_xor(m_a, 32);
      const unsigned e_b = __shfl_xor(m_b, 32);
      union { unsigned u[4]; bf16x8 v; } pb;
      pb.u[0] = hi ? e_a : w0;
      pb.u[1] = hi ? e_b : w1;
      pb.u[2] = hi ? w2 : e_a;
      pb.u[3] = hi ? w3 : e_b;
      o0 = __builtin_amdgcn_mfma_f32_32x32x16_bf16(vv[ks16], pb.v, o0, 0, 0, 0);
      o1 = __builtin_amdgcn_mfma_f32_32x32x16_bf16(vv[4 + ks16], pb.v, o1, 0, 0, 0);
    }
    __builtin_amdgcn_s_setprio(0);

    if (more) {
#pragma unroll
      for (int i = 0; i < 8; ++i) kc[i] = kn[i];
    }
  }

  // write partials: po[slot][q 32][d 64] bf16 (unnormalized), pm/pl per row
  const int slot = b * SEG_PER_B + s;
  __bf16* pop = po + (size_t)slot * 2048;
#pragma unroll
  for (int dt = 0; dt < 2; ++dt) {
    const f32x16& ov = dt ? o1 : o0;
#pragma unroll
    for (int u = 0; u < 4; ++u) {
      uint2 val;
      val.x = cvtpk(ov[4 * u + 0], ov[4 * u + 1]);
      val.y = cvtpk(ov[4 * u + 2], ov[4 * u + 3]);
      *reinterpret_cast<uint2*>(pop + lq * 64 + 8 * u + 4 * hi + 32 * dt) = val;
    }
  }
  if (hi == 0) {
    pm[slot * 32 + lq] = mreg;
    pl[slot * 32 + lq] = lsum;
  }
}

// ---------------------------------------------------------------------------
// Kernel 3: combine <=8 segments per q-tile (32 rows), normalize, f32 out.
__global__ __launch_bounds__(256) void sdpa_combine(
    const __bf16* __restrict__ po, const float* __restrict__ pm,
    const float* __restrict__ pl, float* __restrict__ out) {
  const int bid = blockIdx.x;              // 512: (qt<<3) | b
  const int b = bid & 7, qt = bid >> 3;
  const int mg = qt >> 1;
  int base = 0;
  for (int mm = 0; mm < mg; ++mm) base += 2 * ((mm + 4) >> 2);
  const int cnt = (mg + 4) >> 2;
  base += (qt & 1) ? cnt : 0;
  const int nseg = cnt;                    // ceil(nkt/4), nkt = mg+1
  const int sbase = b * SEG_PER_B + base;
  const int t = threadIdx.x;
  const int r = t >> 3, dc = (t & 7) << 3;

  float M = MASK_VAL;
  for (int s = 0; s < nseg; ++s) M = fmaxf(M, pm[(sbase + s) * 32 + r]);
  float L = 0.f;
  float acc[8] = {0.f, 0.f, 0.f, 0.f, 0.f, 0.f, 0.f, 0.f};
  for (int s = 0; s < nseg; ++s) {
    const int slot = sbase + s;
    const float w = exp2f(fminf((pm[slot * 32 + r] - M) * SOFTMAX_SC, 0.f));
    L += pl[slot * 32 + r] * w;
    const bf16x8 v = *reinterpret_cast<const bf16x8*>(po + (size_t)slot * 2048 + r * 64 + dc);
#pragma unroll
    for (int j = 0; j < 8; ++j) acc[j] += w * (float)v[j];
  }
  const float inv = 1.f / L;
  float4 v0 = {acc[0] * inv, acc[1] * inv, acc[2] * inv, acc[3] * inv};
  float4 v1 = {acc[4] * inv, acc[5] * inv, acc[6] * inv, acc[7] * inv};
  float* dst = out + ((size_t)b * NT + qt * 32 + r) * NH + dc;
  *reinterpret_cast<float4*>(dst) = v0;
  *reinterpret_cast<float4*>(dst + 4) = v1;
}

// ---------------------------------------------------------------------------
extern "C" void kernel_launch(void* const* d_in, const int* in_sizes, int n_in,
                              void* d_out, int out_size, void* d_ws, size_t ws_size,
                              hipStream_t stream) {
  const float* x  = (const float*)d_in[0];
  const float* Wq = (const float*)d_in[1];
  const float* Wk = (const float*)d_in[2];
  const float* Wv = (const float*)d_in[3];
  char* ws = (char*)d_ws;
  __bf16* wswz = (__bf16*)(ws);
  __bf16* Qb   = (__bf16*)(ws + WSWZ_BYTES);
  __bf16* Kb   = (__bf16*)(ws + WSWZ_BYTES + QK_BYTES);
  __bf16* VTb  = (__bf16*)(ws + WSWZ_BYTES + 2 * (size_t)QK_BYTES);
  __bf16* po   = (__bf16*)(ws + PO_OFF);
  float*  pm   = (float*)(ws + PM_OFF);
  float*  pl   = (float*)(ws + PL_OFF);
  float* out = (float*)d_out;

  sdpa_prep_w<<<dim3(384), dim3(64), 0, stream>>>(Wq, Wk, Wv, wswz);
  sdpa_qkv<<<dim3(512), dim3(256), 0, stream>>>(x, wswz, Qb, Kb, VTb);
  sdpa_attn_seg<<<dim3(SLOTS), dim3(64), 0, stream>>>(Qb, Kb, VTb, po, pm, pl);
  sdpa_combine<<<dim3(NB * 64), dim3(256), 0, stream>>>(po, pm, pl, out);
}